// Round 8
// baseline (137.242 us; speedup 1.0000x reference)
//
#include <hip/hip_runtime.h>

// CrossAttention on MI355X (gfx950), round 8.
// B=8 SQ=4096 SKV=77 DE=512 DC=768 H=8 DH=64.
// R8: wave-private barrier-free glds pipeline in both big GEMMs. Each wave
// stages its own A-rows/B-cols (2x dup, L2-hot) into a private 16KB dbuf LDS
// region; counted vmcnt(8) per step; zero __syncthreads in qproj_attn and
// ogemm. LDS 64KB -> 2 blocks/CU.

typedef __attribute__((ext_vector_type(8))) __bf16 bf16x8;
typedef __attribute__((ext_vector_type(4))) float f32x4;

#define DEVI static __device__ __forceinline__

typedef __attribute__((address_space(3))) void lds_void_t;
typedef const __attribute__((address_space(1))) void gbl_void_t;
#define GLDS16(gsrc, ldst) \
  __builtin_amdgcn_global_load_lds((gbl_void_t*)(gsrc), (lds_void_t*)(ldst), 16, 0, 0)

DEVI unsigned short f2bf(float f) {
  unsigned int u = __float_as_uint(f);
  u += 0x7FFFu + ((u >> 16) & 1u);   // round-to-nearest-even
  return (unsigned short)(u >> 16);
}

DEVI unsigned int pack2bf(float a, float b) {
  return (unsigned int)f2bf(a) | ((unsigned int)f2bf(b) << 16);
}

// ---------------------------------------------------------------------------
// latent fp32 -> bf16, 8 elems/thread
// ---------------------------------------------------------------------------
__global__ __launch_bounds__(256) void cvt_bf16_kernel(const float* __restrict__ in,
                                                       unsigned int* __restrict__ out4) {
  int i = blockIdx.x * 256 + threadIdx.x;
  const float4* in4 = (const float4*)in;
  float4 a = in4[2 * i];
  float4 b = in4[2 * i + 1];
  uint4 o;
  o.x = pack2bf(a.x, a.y);
  o.y = pack2bf(a.z, a.w);
  o.z = pack2bf(b.x, b.y);
  o.w = pack2bf(b.z, b.w);
  *(uint4*)(out4 + 4 * (size_t)i) = o;
}

// ---------------------------------------------------------------------------
// All 4 weight transposes in one launch. in [K][N=512] f32 -> out [N][K] bf16.
// ---------------------------------------------------------------------------
__global__ __launch_bounds__(256) void wtrans_all_kernel(
    const float* __restrict__ wq, const float* __restrict__ wk,
    const float* __restrict__ wv, const float* __restrict__ wo,
    unsigned short* __restrict__ wqT, unsigned short* __restrict__ wkT,
    unsigned short* __restrict__ wvT, unsigned short* __restrict__ woT) {
  __shared__ float tile[32][33];
  int bid = blockIdx.x;
  const float* in;
  unsigned short* out;
  int K, r;
  if (bid < 256)       { in = wq; out = wqT; K = 512; r = bid; }
  else if (bid < 640)  { in = wk; out = wkT; K = 768; r = bid - 256; }
  else if (bid < 1024) { in = wv; out = wvT; K = 768; r = bid - 640; }
  else                 { in = wo; out = woT; K = 512; r = bid - 1024; }
  int n0 = (r & 15) * 32, k0 = (r >> 4) * 32;
  int tx = threadIdx.x, ty = threadIdx.y;
#pragma unroll
  for (int j = 0; j < 4; ++j)
    tile[ty * 4 + j][tx] = in[(size_t)(k0 + ty * 4 + j) * 512 + n0 + tx];
  __syncthreads();
#pragma unroll
  for (int j = 0; j < 4; ++j)
    out[(size_t)(n0 + ty * 4 + j) * K + k0 + tx] = f2bf(tile[tx][ty * 4 + j]);
}

// ---------------------------------------------------------------------------
// K/V projection (unchanged, proven)
// ---------------------------------------------------------------------------
__global__ __launch_bounds__(256) void kv_proj_kernel(const float* __restrict__ ctx,
                                                      const unsigned short* __restrict__ wkT,
                                                      const unsigned short* __restrict__ wvT,
                                                      const float* __restrict__ bk,
                                                      const float* __restrict__ bv,
                                                      unsigned short* __restrict__ Kp,
                                                      unsigned short* __restrict__ Vt) {
  __shared__ __align__(16) unsigned short As[64][40];
  __shared__ __align__(16) unsigned short Bs[64][40];
  int bid = blockIdx.x;
  int sel = bid / 80;
  int rem = bid % 80;
  int mt = rem / 8, nt = rem % 8;
  const unsigned short* wT = sel ? wvT : wkT;
  const float* bias = sel ? bv : bk;
  int tid = threadIdx.x;
  int l = tid & 63, w = tid >> 6;
  int lr = l & 15, lg = l >> 4;

  f32x4 acc[4] = {};
  for (int k0 = 0; k0 < 768; k0 += 32) {
#pragma unroll
    for (int it = 0; it < 2; ++it) {
      int idx4 = it * 256 + tid;
      int r = idx4 >> 3, q4 = idx4 & 7;
      int m = mt * 64 + r;
      float4 v = {0.f, 0.f, 0.f, 0.f};
      if (m < 616) v = *(const float4*)(ctx + (size_t)m * 768 + k0 + q4 * 4);
      ushort4 o;
      o.x = f2bf(v.x); o.y = f2bf(v.y); o.z = f2bf(v.z); o.w = f2bf(v.w);
      *(ushort4*)&As[r][q4 * 4] = o;
    }
    {
      int c = tid >> 2, q8 = tid & 3;
      *(uint4*)&Bs[c][q8 * 8] =
          *(const uint4*)(wT + (size_t)(nt * 64 + c) * 768 + k0 + q8 * 8);
    }
    __syncthreads();
    bf16x8 a = *(const bf16x8*)&As[w * 16 + lr][lg * 8];
#pragma unroll
    for (int n = 0; n < 4; ++n) {
      bf16x8 bb = *(const bf16x8*)&Bs[n * 16 + lr][lg * 8];
      acc[n] = __builtin_amdgcn_mfma_f32_16x16x32_bf16(a, bb, acc[n], 0, 0, 0);
    }
    __syncthreads();
  }
#pragma unroll
  for (int n = 0; n < 4; ++n) {
#pragma unroll
    for (int reg = 0; reg < 4; ++reg) {
      int m = mt * 64 + w * 16 + lg * 4 + reg;
      if (m < 616) {
        int bI = m / 77, s = m % 77;
        int col = nt * 64 + n * 16 + lr;
        int h = col >> 6, d = col & 63;
        float v = acc[n][reg] + bias[col];
        if (sel == 0)
          Kp[(((size_t)(bI * 8 + h)) * 80 + s) * 64 + d] = f2bf(v);
        else
          Vt[(((size_t)(bI * 8 + h)) * 64 + d) * 96 + s] = f2bf(v);
      }
    }
  }
}

// ---------------------------------------------------------------------------
// FUSED Q-proj + attention, v6: wave-private barrier-free glds pipeline.
// Per-wave LDS region = 8192 elems (16KB): buf b -> A at b*4096, B at
// b*4096+2048. Attn overlay (Qw 64x72 = 4608 elems) also inside the wave's
// own region. NO __syncthreads in this kernel.
// ---------------------------------------------------------------------------
__global__ __launch_bounds__(256, 2) void qproj_attn_kernel(
    const unsigned short* __restrict__ A, const unsigned short* __restrict__ BT,
    const float* __restrict__ bias, const unsigned short* __restrict__ Kp,
    const unsigned short* __restrict__ Vt, unsigned short* __restrict__ Oq) {
  __shared__ __align__(16) unsigned short smem[32768];  // 64 KB

  // XCD-bijective swizzle (1024 blocks, 8 XCDs): A-panel siblings contiguous.
  int bid = ((blockIdx.x & 7) << 7) | (blockIdx.x >> 3);
  size_t mbase = (size_t)(bid >> 2) * 128;
  int nbase = (bid & 3) * 128;
  int tid = threadIdx.x;
  int l = tid & 63, w = tid >> 6;
  int lr = l & 15, lg = l >> 4;
  int wr = (w >> 1) * 64, wc = (w & 1) * 64;

  unsigned short* wbase = smem + w * 8192;  // per-wave 16 KB

  // per-lane global staging addrs: chunk c covers rows c*16+(l>>2), 16B each
  const unsigned short* gA = A + (mbase + wr + (l >> 2)) * 512 + (l & 3) * 8;
  const unsigned short* gB = BT + (size_t)(nbase + wc + (l >> 2)) * 512 + (l & 3) * 8;

  auto stage = [&](int k0, int b) {
#pragma unroll
    for (int c = 0; c < 4; ++c) {
      GLDS16(gA + (size_t)(c * 16) * 512 + k0, wbase + b * 4096 + c * 512);
      GLDS16(gB + (size_t)(c * 16) * 512 + k0, wbase + b * 4096 + 2048 + c * 512);
    }
  };

  f32x4 acc[4][4] = {};
  stage(0, 0);
#pragma unroll
  for (int t = 0; t < 16; ++t) {
    const int cur = t & 1;
    if (t < 15) {
      // buf cur^1 held batch t-1; its ds_reads were consumed at step t-1.
      asm volatile("s_waitcnt lgkmcnt(0)" ::: "memory");
      stage((t + 1) * 32, cur ^ 1);
      asm volatile("s_waitcnt vmcnt(8)" ::: "memory");  // batch t landed
    } else {
      asm volatile("s_waitcnt vmcnt(0)" ::: "memory");
    }
    const unsigned short* bufA = wbase + cur * 4096;
    const unsigned short* bufB = bufA + 2048;
    bf16x8 af[4], bv8[4];
#pragma unroll
    for (int m = 0; m < 4; ++m)
      af[m] = *(const bf16x8*)&bufA[(m * 16 + lr) * 32 + lg * 8];
#pragma unroll
    for (int n = 0; n < 4; ++n)
      bv8[n] = *(const bf16x8*)&bufB[(n * 16 + lr) * 32 + lg * 8];
#pragma unroll
    for (int m = 0; m < 4; ++m)
#pragma unroll
      for (int n = 0; n < 4; ++n)
        acc[m][n] = __builtin_amdgcn_mfma_f32_16x16x32_bf16(af[m], bv8[n], acc[m][n], 0, 0, 0);
  }

  // ---- epilogue: Q quadrant -> wave-private LDS (transpose), +bias ----
  // DS queue is in-order per wave -> ds_writes follow the loop's ds_reads.
  unsigned short* Qme = wbase;  // [64][72] = 4608 elems <= 8192
  float bb[4];
#pragma unroll
  for (int n = 0; n < 4; ++n) bb[n] = bias[nbase + wc + n * 16 + lr];
#pragma unroll
  for (int m = 0; m < 4; ++m)
#pragma unroll
    for (int n = 0; n < 4; ++n)
#pragma unroll
      for (int reg = 0; reg < 4; ++reg)
        Qme[(m * 16 + lg * 4 + reg) * 72 + n * 16 + lr] = f2bf(acc[m][n][reg] + bb[n]);

  // preload ALL Q frags to regs (wave-local LDS RAW: compiler orders)
  bf16x8 qf[4][2];
#pragma unroll
  for (int rg = 0; rg < 4; ++rg) {
    qf[rg][0] = *(const bf16x8*)&Qme[(rg * 16 + lr) * 72 + lg * 8];
    qf[rg][1] = *(const bf16x8*)&Qme[(rg * 16 + lr) * 72 + 32 + lg * 8];
  }

  // wave-private P inside this wave's dead Qw region (16 x 104 bf16)
  unsigned short* Pme = Qme;
  for (int z = l; z < 256; z += 64) Pme[(z >> 4) * 104 + 80 + (z & 15)] = 0;

  // ---- wave-local attention: 64 q-rows x head h ----
  int b = (int)(mbase >> 12);
  int h = (bid & 3) * 2 + (w & 1);
  const unsigned short* Kph = Kp + (size_t)(b * 8 + h) * (80 * 64);
  const unsigned short* Vth = Vt + (size_t)(b * 8 + h) * (64 * 96);

  const float C = 0.125f * 1.44269504088896f;  // 1/sqrt(64) * log2(e)

  auto QK = [&](int rg, f32x4* s) {
#pragma unroll
    for (int t = 0; t < 5; ++t) {
      const unsigned short* kr = Kph + (t * 16 + lr) * 64 + lg * 8;
      bf16x8 k0 = *(const bf16x8*)kr;
      bf16x8 k1 = *(const bf16x8*)(kr + 32);
      s[t] = __builtin_amdgcn_mfma_f32_16x16x32_bf16(qf[rg][0], k0, s[t], 0, 0, 0);
      s[t] = __builtin_amdgcn_mfma_f32_16x16x32_bf16(qf[rg][1], k1, s[t], 0, 0, 0);
    }
    if (lr >= 13) {  // cols 64+lr >= 77 are pad
      s[4][0] = -1e30f; s[4][1] = -1e30f; s[4][2] = -1e30f; s[4][3] = -1e30f;
    }
  };

  f32x4 sc[5] = {};
  QK(0, sc);
#pragma unroll
  for (int rg = 0; rg < 4; ++rg) {
    float mx[4];
#pragma unroll
    for (int r = 0; r < 4; ++r)
      mx[r] = fmaxf(fmaxf(fmaxf(sc[0][r], sc[1][r]), fmaxf(sc[2][r], sc[3][r])), sc[4][r]);
#pragma unroll
    for (int d = 1; d < 16; d <<= 1)
#pragma unroll
      for (int r = 0; r < 4; ++r) mx[r] = fmaxf(mx[r], __shfl_xor(mx[r], d, 64));
    // unnormalized exp -> P (normalization deferred to after PV)
    float p[5][4];
#pragma unroll
    for (int t = 0; t < 5; ++t)
#pragma unroll
      for (int r = 0; r < 4; ++r) p[t][r] = exp2f((sc[t][r] - mx[r]) * C);
#pragma unroll
    for (int t = 0; t < 5; ++t)
#pragma unroll
      for (int r = 0; r < 4; ++r)
        Pme[(lg * 4 + r) * 104 + t * 16 + lr] = f2bf(p[t][r]);

    float sm[4];
#pragma unroll
    for (int r = 0; r < 4; ++r)
      sm[r] = p[0][r] + p[1][r] + p[2][r] + p[3][r] + p[4][r];
#pragma unroll
    for (int d = 1; d < 16; d <<= 1)
#pragma unroll
      for (int r = 0; r < 4; ++r) sm[r] += __shfl_xor(sm[r], d, 64);
    float rs[4];
#pragma unroll
    for (int r = 0; r < 4; ++r) rs[r] = 1.0f / sm[r];

    // next QK (pure-reg MFMA + L1-hot K loads) overlaps softmax/PV
    f32x4 sn[5] = {};
    if (rg < 3) QK(rg + 1, sn);

    bf16x8 ap[3];
#pragma unroll
    for (int c = 0; c < 3; ++c) ap[c] = *(const bf16x8*)&Pme[lr * 104 + c * 32 + lg * 8];
#pragma unroll
    for (int ct = 0; ct < 4; ++ct) {
      f32x4 o = {};
#pragma unroll
      for (int c = 0; c < 3; ++c) {
        bf16x8 vv = *(const bf16x8*)(Vth + (size_t)(ct * 16 + lr) * 96 + c * 32 + lg * 8);
        o = __builtin_amdgcn_mfma_f32_16x16x32_bf16(ap[c], vv, o, 0, 0, 0);
      }
#pragma unroll
      for (int reg = 0; reg < 4; ++reg)
        Oq[(mbase + wr + rg * 16 + lg * 4 + reg) * 512 + nbase + wc + ct * 16 + lr] =
            f2bf(o[reg] * rs[reg]);
    }
#pragma unroll
    for (int t = 0; t < 5; ++t) sc[t] = sn[t];
  }
}

// ---------------------------------------------------------------------------
// O-proj GEMM: wave-private barrier-free glds pipeline + XCD swizzle.
// A [32768][512] bf16 @ woT [512][512] bf16 + bo -> f32.
// ---------------------------------------------------------------------------
__global__ __launch_bounds__(256, 2) void gemm512_glds_kernel(
    const unsigned short* __restrict__ A, const unsigned short* __restrict__ BT,
    const float* __restrict__ bias, float* __restrict__ Out) {
  __shared__ __align__(16) unsigned short smem[32768];  // 64 KB
  int bid = ((blockIdx.x & 7) << 7) | (blockIdx.x >> 3);  // XCD swizzle
  size_t mbase = (size_t)(bid >> 2) * 128;
  int nbase = (bid & 3) * 128;
  int tid = threadIdx.x;
  int l = tid & 63, w = tid >> 6;
  int lr = l & 15, lg = l >> 4;
  int wr = (w >> 1) * 64, wc = (w & 1) * 64;

  unsigned short* wbase = smem + w * 8192;
  const unsigned short* gA = A + (mbase + wr + (l >> 2)) * 512 + (l & 3) * 8;
  const unsigned short* gB = BT + (size_t)(nbase + wc + (l >> 2)) * 512 + (l & 3) * 8;

  auto stage = [&](int k0, int b) {
#pragma unroll
    for (int c = 0; c < 4; ++c) {
      GLDS16(gA + (size_t)(c * 16) * 512 + k0, wbase + b * 4096 + c * 512);
      GLDS16(gB + (size_t)(c * 16) * 512 + k0, wbase + b * 4096 + 2048 + c * 512);
    }
  };

  f32x4 acc[4][4] = {};
  stage(0, 0);
#pragma unroll
  for (int t = 0; t < 16; ++t) {
    const int cur = t & 1;
    if (t < 15) {
      asm volatile("s_waitcnt lgkmcnt(0)" ::: "memory");
      stage((t + 1) * 32, cur ^ 1);
      asm volatile("s_waitcnt vmcnt(8)" ::: "memory");
    } else {
      asm volatile("s_waitcnt vmcnt(0)" ::: "memory");
    }
    const unsigned short* bufA = wbase + cur * 4096;
    const unsigned short* bufB = bufA + 2048;
    bf16x8 af[4], bv8[4];
#pragma unroll
    for (int m = 0; m < 4; ++m)
      af[m] = *(const bf16x8*)&bufA[(m * 16 + lr) * 32 + lg * 8];
#pragma unroll
    for (int n = 0; n < 4; ++n)
      bv8[n] = *(const bf16x8*)&bufB[(n * 16 + lr) * 32 + lg * 8];
#pragma unroll
    for (int m = 0; m < 4; ++m)
#pragma unroll
      for (int n = 0; n < 4; ++n)
        acc[m][n] = __builtin_amdgcn_mfma_f32_16x16x32_bf16(af[m], bv8[n], acc[m][n], 0, 0, 0);
  }
#pragma unroll
  for (int m = 0; m < 4; ++m) {
#pragma unroll
    for (int n = 0; n < 4; ++n) {
#pragma unroll
      for (int reg = 0; reg < 4; ++reg) {
        size_t row = mbase + wr + m * 16 + lg * 4 + reg;
        int col = nbase + wc + n * 16 + lr;
        Out[row * 512 + col] = acc[m][n][reg] + bias[col];
      }
    }
  }
}

// ---------------------------------------------------------------------------
// Workspace layout (bytes)
// ---------------------------------------------------------------------------
static const size_t OFF_Q   = 0;                         // 8*4096*512*2 = 33554432
static const size_t OFF_KP  = 33554432;                  // 8*8*80*64*2  = 655360
static const size_t OFF_VT  = OFF_KP + 655360;           // 8*8*64*96*2  = 786432
static const size_t OFF_WQT = OFF_VT + 786432;           // 512*512*2
static const size_t OFF_WKT = OFF_WQT + 524288;          // 512*768*2
static const size_t OFF_WVT = OFF_WKT + 786432;          // 512*768*2
static const size_t OFF_WOT = OFF_WVT + 786432;          // 512*512*2
static const size_t WS_NEEDED = OFF_WOT + 524288;        // 37617664

extern "C" void kernel_launch(void* const* d_in, const int* in_sizes, int n_in,
                              void* d_out, int out_size, void* d_ws, size_t ws_size,
                              hipStream_t stream) {
  (void)in_sizes; (void)n_in; (void)out_size;
  if (ws_size < WS_NEEDED) return;

  const float* latent  = (const float*)d_in[0];
  const float* context = (const float*)d_in[1];
  const float* wq = (const float*)d_in[2];
  const float* bq = (const float*)d_in[3];
  const float* wk = (const float*)d_in[4];
  const float* bk = (const float*)d_in[5];
  const float* wv = (const float*)d_in[6];
  const float* bv = (const float*)d_in[7];
  const float* wo = (const float*)d_in[8];
  const float* bo = (const float*)d_in[9];
  float* out = (float*)d_out;

  char* ws = (char*)d_ws;
  unsigned short* wsQ = (unsigned short*)(ws + OFF_Q);   // attn output (bf16)
  unsigned short* Kp  = (unsigned short*)(ws + OFF_KP);
  unsigned short* Vt  = (unsigned short*)(ws + OFF_VT);
  unsigned short* wqT = (unsigned short*)(ws + OFF_WQT);
  unsigned short* wkT = (unsigned short*)(ws + OFF_WKT);
  unsigned short* wvT = (unsigned short*)(ws + OFF_WVT);
  unsigned short* woT = (unsigned short*)(ws + OFF_WOT);

  // latent bf16 parked in d_out (first 33.5MB); consumed by qproj, then
  // d_out fully rewritten by the final GEMM.
  unsigned short* latBF = (unsigned short*)d_out;

  wtrans_all_kernel<<<1280, dim3(32, 8), 0, stream>>>(wq, wk, wv, wo,
                                                      wqT, wkT, wvT, woT);
  hipMemsetAsync(ws + OFF_KP, 0, 655360 + 786432, stream);
  kv_proj_kernel<<<160, 256, 0, stream>>>(context, wkT, wvT, bk, bv, Kp, Vt);
  cvt_bf16_kernel<<<8192, 256, 0, stream>>>(latent, (unsigned int*)latBF);
  qproj_attn_kernel<<<1024, 256, 0, stream>>>(latBF, wqT, bq, Kp, Vt, wsQ);
  gemm512_glds_kernel<<<1024, 256, 0, stream>>>(wsQ, woT, bo, out);
}

// Round 10
// 125.079 us; speedup vs baseline: 1.0972x; 1.0972x over previous
//
#include <hip/hip_runtime.h>

// CrossAttention on MI355X (gfx950), round 10.
// B=8 SQ=4096 SKV=77 DE=512 DC=768 H=8 DH=64.
// R10 = R9 with the LDS buffer-layout bug fixed: buffer b at elem offset
// b*8192, A at +0 (4096 elems = 128 rows x 32), B at +4096. R9 had B at
// +2048 which collided with A (absmax 88.9). Counted-vmcnt schedule (T4)
// unchanged: vmcnt(4) in steady state, never drained to 0 inside the loop.

typedef __attribute__((ext_vector_type(8))) __bf16 bf16x8;
typedef __attribute__((ext_vector_type(4))) float f32x4;

#define DEVI static __device__ __forceinline__

typedef __attribute__((address_space(3))) void lds_void_t;
typedef const __attribute__((address_space(1))) void gbl_void_t;
#define GLDS16(gsrc, ldst) \
  __builtin_amdgcn_global_load_lds((gbl_void_t*)(gsrc), (lds_void_t*)(ldst), 16, 0, 0)

DEVI unsigned short f2bf(float f) {
  unsigned int u = __float_as_uint(f);
  u += 0x7FFFu + ((u >> 16) & 1u);   // round-to-nearest-even
  return (unsigned short)(u >> 16);
}

DEVI unsigned int pack2bf(float a, float b) {
  return (unsigned int)f2bf(a) | ((unsigned int)f2bf(b) << 16);
}

// ---------------------------------------------------------------------------
// PREP: blocks [0,1280) = 4 weight transposes ([K][512]f32 -> [512][K]bf16);
//       blocks [1280,9472) = latent fp32->bf16 (8 elems/thread).
// ---------------------------------------------------------------------------
__global__ __launch_bounds__(256) void prep_kernel(
    const float* __restrict__ wq, const float* __restrict__ wk,
    const float* __restrict__ wv, const float* __restrict__ wo,
    unsigned short* __restrict__ wqT, unsigned short* __restrict__ wkT,
    unsigned short* __restrict__ wvT, unsigned short* __restrict__ woT,
    const float* __restrict__ latent, unsigned int* __restrict__ latBF4) {
  int bid = blockIdx.x;
  int tid = threadIdx.x;
  if (bid >= 1280) {  // ---- cvt part ----
    size_t i = (size_t)(bid - 1280) * 256 + tid;
    const float4* in4 = (const float4*)latent;
    float4 a = in4[2 * i];
    float4 b = in4[2 * i + 1];
    uint4 o;
    o.x = pack2bf(a.x, a.y);
    o.y = pack2bf(a.z, a.w);
    o.z = pack2bf(b.x, b.y);
    o.w = pack2bf(b.z, b.w);
    *(uint4*)(latBF4 + 4 * i) = o;
    return;
  }
  // ---- wtrans part ----
  __shared__ float tile[32][33];
  const float* in;
  unsigned short* out;
  int K, r;
  if (bid < 256)       { in = wq; out = wqT; K = 512; r = bid; }
  else if (bid < 640)  { in = wk; out = wkT; K = 768; r = bid - 256; }
  else if (bid < 1024) { in = wv; out = wvT; K = 768; r = bid - 640; }
  else                 { in = wo; out = woT; K = 512; r = bid - 1024; }
  int n0 = (r & 15) * 32, k0 = (r >> 4) * 32;
  int tx = tid & 31, ty = tid >> 5;
#pragma unroll
  for (int j = 0; j < 4; ++j)
    tile[ty * 4 + j][tx] = in[(size_t)(k0 + ty * 4 + j) * 512 + n0 + tx];
  __syncthreads();
#pragma unroll
  for (int j = 0; j < 4; ++j)
    out[(size_t)(n0 + ty * 4 + j) * K + k0 + tx] = f2bf(tile[tx][ty * 4 + j]);
}

// ---------------------------------------------------------------------------
// K/V projection (unchanged, proven)
// ---------------------------------------------------------------------------
__global__ __launch_bounds__(256) void kv_proj_kernel(const float* __restrict__ ctx,
                                                      const unsigned short* __restrict__ wkT,
                                                      const unsigned short* __restrict__ wvT,
                                                      const float* __restrict__ bk,
                                                      const float* __restrict__ bv,
                                                      unsigned short* __restrict__ Kp,
                                                      unsigned short* __restrict__ Vt) {
  __shared__ __align__(16) unsigned short As[64][40];
  __shared__ __align__(16) unsigned short Bs[64][40];
  int bid = blockIdx.x;
  int sel = bid / 80;
  int rem = bid % 80;
  int mt = rem / 8, nt = rem % 8;
  const unsigned short* wT = sel ? wvT : wkT;
  const float* bias = sel ? bv : bk;
  int tid = threadIdx.x;
  int l = tid & 63, w = tid >> 6;
  int lr = l & 15, lg = l >> 4;

  f32x4 acc[4] = {};
  for (int k0 = 0; k0 < 768; k0 += 32) {
#pragma unroll
    for (int it = 0; it < 2; ++it) {
      int idx4 = it * 256 + tid;
      int r = idx4 >> 3, q4 = idx4 & 7;
      int m = mt * 64 + r;
      float4 v = {0.f, 0.f, 0.f, 0.f};
      if (m < 616) v = *(const float4*)(ctx + (size_t)m * 768 + k0 + q4 * 4);
      ushort4 o;
      o.x = f2bf(v.x); o.y = f2bf(v.y); o.z = f2bf(v.z); o.w = f2bf(v.w);
      *(ushort4*)&As[r][q4 * 4] = o;
    }
    {
      int c = tid >> 2, q8 = tid & 3;
      *(uint4*)&Bs[c][q8 * 8] =
          *(const uint4*)(wT + (size_t)(nt * 64 + c) * 768 + k0 + q8 * 8);
    }
    __syncthreads();
    bf16x8 a = *(const bf16x8*)&As[w * 16 + lr][lg * 8];
#pragma unroll
    for (int n = 0; n < 4; ++n) {
      bf16x8 bb = *(const bf16x8*)&Bs[n * 16 + lr][lg * 8];
      acc[n] = __builtin_amdgcn_mfma_f32_16x16x32_bf16(a, bb, acc[n], 0, 0, 0);
    }
    __syncthreads();
  }
#pragma unroll
  for (int n = 0; n < 4; ++n) {
#pragma unroll
    for (int reg = 0; reg < 4; ++reg) {
      int m = mt * 64 + w * 16 + lg * 4 + reg;
      if (m < 616) {
        int bI = m / 77, s = m % 77;
        int col = nt * 64 + n * 16 + lr;
        int h = col >> 6, d = col & 63;
        float v = acc[n][reg] + bias[col];
        if (sel == 0)
          Kp[(((size_t)(bI * 8 + h)) * 80 + s) * 64 + d] = f2bf(v);
        else
          Vt[(((size_t)(bI * 8 + h)) * 64 + d) * 96 + s] = f2bf(v);
      }
    }
  }
}

// ---------------------------------------------------------------------------
// Counted-vmcnt K-step, shared by both GEMMs.
// Buffer b at elem offset b*8192: A at +0 (128 rows x 32), B at +4096.
// Per wave per step: 4 GLDS (A x2, B x2). Steady in-flight = 8; wait vmcnt(4).
// ---------------------------------------------------------------------------
#define KSTEP(t, boff)                                                        \
  {                                                                           \
    if ((t) < 15)                                                             \
      asm volatile("s_waitcnt vmcnt(4)" ::: "memory");                        \
    else                                                                      \
      asm volatile("s_waitcnt vmcnt(0)" ::: "memory");                        \
    __builtin_amdgcn_s_barrier();                                             \
    __builtin_amdgcn_sched_barrier(0);                                        \
    const unsigned short* bufA = smem + (boff);                               \
    const unsigned short* bufB = bufA + 4096;                                 \
    bf16x8 af[4], bv8[4];                                                     \
    _Pragma("unroll") for (int m = 0; m < 4; ++m)                             \
        af[m] = *(const bf16x8*)&bufA[(wr + m * 16 + lr) * 32 + lg * 8];      \
    _Pragma("unroll") for (int n = 0; n < 4; ++n)                             \
        bv8[n] = *(const bf16x8*)&bufB[(wc + n * 16 + lr) * 32 + lg * 8];     \
    asm volatile("s_waitcnt lgkmcnt(0)" ::: "memory");                        \
    __builtin_amdgcn_sched_barrier(0);                                        \
    __builtin_amdgcn_s_barrier();                                             \
    if ((t) <= 13) {                                                          \
      int nk = ((t) + 2) * 32;                                                \
      GLDS16(gA + nk, smem + (boff) + w * 1024);                              \
      GLDS16(gA + nk + 16 * 512, smem + (boff) + w * 1024 + 512);             \
      GLDS16(gB + nk, smem + (boff) + 4096 + w * 1024);                       \
      GLDS16(gB + nk + 16 * 512, smem + (boff) + 4096 + w * 1024 + 512);      \
    }                                                                         \
    _Pragma("unroll") for (int m = 0; m < 4; ++m)                             \
        _Pragma("unroll") for (int n = 0; n < 4; ++n)                         \
            acc[m][n] = __builtin_amdgcn_mfma_f32_16x16x32_bf16(              \
                af[m], bv8[n], acc[m][n], 0, 0, 0);                           \
  }

// ---------------------------------------------------------------------------
// FUSED Q-proj + attention: counted-vmcnt GEMM + wave-private attn tail.
// LDS 36864 B (GEMM dbuf 32KB at [0,16384) elems; attn Qw overlay 36KB)
// -> 4 blocks/CU.
// ---------------------------------------------------------------------------
__global__ __launch_bounds__(256, 4) void qproj_attn_kernel(
    const unsigned short* __restrict__ A, const unsigned short* __restrict__ BT,
    const float* __restrict__ bias, const unsigned short* __restrict__ Kp,
    const unsigned short* __restrict__ Vt, unsigned short* __restrict__ Oq) {
  __shared__ __align__(16) unsigned short smem[18432];  // 36864 B

  int bid = ((blockIdx.x & 7) << 7) | (blockIdx.x >> 3);  // XCD swizzle
  size_t mbase = (size_t)(bid >> 2) * 128;
  int nbase = (bid & 3) * 128;
  int tid = threadIdx.x;
  int l = tid & 63, w = tid >> 6;
  int lr = l & 15, lg = l >> 4;
  int wr = (w >> 1) * 64, wc = (w & 1) * 64;

  const unsigned short* gA = A + (mbase + w * 32 + (l >> 2)) * 512 + (l & 3) * 8;
  const unsigned short* gB = BT + (size_t)(nbase + w * 32 + (l >> 2)) * 512 + (l & 3) * 8;

  // prologue: batch 0 -> buf0 (A@0, B@4096), batch 1 -> buf1 (A@8192, B@12288)
  GLDS16(gA, smem + w * 1024);
  GLDS16(gA + 16 * 512, smem + w * 1024 + 512);
  GLDS16(gB, smem + 4096 + w * 1024);
  GLDS16(gB + 16 * 512, smem + 4096 + w * 1024 + 512);
  GLDS16(gA + 32, smem + 8192 + w * 1024);
  GLDS16(gA + 32 + 16 * 512, smem + 8192 + w * 1024 + 512);
  GLDS16(gB + 32, smem + 12288 + w * 1024);
  GLDS16(gB + 32 + 16 * 512, smem + 12288 + w * 1024 + 512);

  f32x4 acc[4][4] = {};
#pragma unroll 1
  for (int t = 0; t < 16; t += 2) {
    KSTEP(t, 0);
    KSTEP(t + 1, 8192);
  }

  // ---- epilogue: Q quadrant -> wave-private LDS (transpose), +bias ----
  // Step-15's second barrier guaranteed all waves' ds_reads complete.
  unsigned short* Qme = smem + w * (64 * 72);
  float bb[4];
#pragma unroll
  for (int n = 0; n < 4; ++n) bb[n] = bias[nbase + wc + n * 16 + lr];
#pragma unroll
  for (int m = 0; m < 4; ++m)
#pragma unroll
    for (int n = 0; n < 4; ++n)
#pragma unroll
      for (int reg = 0; reg < 4; ++reg)
        Qme[(m * 16 + lg * 4 + reg) * 72 + n * 16 + lr] = f2bf(acc[m][n][reg] + bb[n]);

  bf16x8 qf[4][2];
#pragma unroll
  for (int rg = 0; rg < 4; ++rg) {
    qf[rg][0] = *(const bf16x8*)&Qme[(rg * 16 + lr) * 72 + lg * 8];
    qf[rg][1] = *(const bf16x8*)&Qme[(rg * 16 + lr) * 72 + 32 + lg * 8];
  }

  // wave-private P inside this wave's dead Qw region (16 x 104 bf16)
  unsigned short* Pme = Qme;
  for (int z = l; z < 256; z += 64) Pme[(z >> 4) * 104 + 80 + (z & 15)] = 0;

  // ---- wave-local attention: 64 q-rows x head h ----
  int b = (int)(mbase >> 12);
  int h = (bid & 3) * 2 + (w & 1);
  const unsigned short* Kph = Kp + (size_t)(b * 8 + h) * (80 * 64);
  const unsigned short* Vth = Vt + (size_t)(b * 8 + h) * (64 * 96);

  const float C = 0.125f * 1.44269504088896f;  // 1/sqrt(64) * log2(e)

  auto QK = [&](int rg, f32x4* s) {
#pragma unroll
    for (int t = 0; t < 5; ++t) {
      const unsigned short* kr = Kph + (t * 16 + lr) * 64 + lg * 8;
      bf16x8 k0 = *(const bf16x8*)kr;
      bf16x8 k1 = *(const bf16x8*)(kr + 32);
      s[t] = __builtin_amdgcn_mfma_f32_16x16x32_bf16(qf[rg][0], k0, s[t], 0, 0, 0);
      s[t] = __builtin_amdgcn_mfma_f32_16x16x32_bf16(qf[rg][1], k1, s[t], 0, 0, 0);
    }
    if (lr >= 13) {  // cols 64+lr >= 77 are pad
      s[4][0] = -1e30f; s[4][1] = -1e30f; s[4][2] = -1e30f; s[4][3] = -1e30f;
    }
  };

  f32x4 sc[5] = {};
  QK(0, sc);
#pragma unroll
  for (int rg = 0; rg < 4; ++rg) {
    float mx[4];
#pragma unroll
    for (int r = 0; r < 4; ++r)
      mx[r] = fmaxf(fmaxf(fmaxf(sc[0][r], sc[1][r]), fmaxf(sc[2][r], sc[3][r])), sc[4][r]);
#pragma unroll
    for (int d = 1; d < 16; d <<= 1)
#pragma unroll
      for (int r = 0; r < 4; ++r) mx[r] = fmaxf(mx[r], __shfl_xor(mx[r], d, 64));
    float p[5][4];
#pragma unroll
    for (int t = 0; t < 5; ++t)
#pragma unroll
      for (int r = 0; r < 4; ++r) p[t][r] = exp2f((sc[t][r] - mx[r]) * C);
#pragma unroll
    for (int t = 0; t < 5; ++t)
#pragma unroll
      for (int r = 0; r < 4; ++r)
        Pme[(lg * 4 + r) * 104 + t * 16 + lr] = f2bf(p[t][r]);

    float sm[4];
#pragma unroll
    for (int r = 0; r < 4; ++r)
      sm[r] = p[0][r] + p[1][r] + p[2][r] + p[3][r] + p[4][r];
#pragma unroll
    for (int d = 1; d < 16; d <<= 1)
#pragma unroll
      for (int r = 0; r < 4; ++r) sm[r] += __shfl_xor(sm[r], d, 64);
    float rs[4];
#pragma unroll
    for (int r = 0; r < 4; ++r) rs[r] = 1.0f / sm[r];

    f32x4 sn[5] = {};
    if (rg < 3) QK(rg + 1, sn);

    bf16x8 ap[3];
#pragma unroll
    for (int c = 0; c < 3; ++c) ap[c] = *(const bf16x8*)&Pme[lr * 104 + c * 32 + lg * 8];
#pragma unroll
    for (int ct = 0; ct < 4; ++ct) {
      f32x4 o = {};
#pragma unroll
      for (int c = 0; c < 3; ++c) {
        bf16x8 vv = *(const bf16x8*)(Vth + (size_t)(ct * 16 + lr) * 96 + c * 32 + lg * 8);
        o = __builtin_amdgcn_mfma_f32_16x16x32_bf16(ap[c], vv, o, 0, 0, 0);
      }
#pragma unroll
      for (int reg = 0; reg < 4; ++reg)
        Oq[(mbase + wr + rg * 16 + lg * 4 + reg) * 512 + nbase + wc + ct * 16 + lr] =
            f2bf(o[reg] * rs[reg]);
    }
#pragma unroll
    for (int t = 0; t < 5; ++t) sc[t] = sn[t];
  }
}

// ---------------------------------------------------------------------------
// O-proj GEMM: counted-vmcnt pipeline + XCD swizzle.
// A [32768][512] bf16 @ woT [512][512] bf16 + bo -> f32. LDS 32768 B.
// ---------------------------------------------------------------------------
__global__ __launch_bounds__(256) void gemm512_glds_kernel(
    const unsigned short* __restrict__ A, const unsigned short* __restrict__ BT,
    const float* __restrict__ bias, float* __restrict__ Out) {
  __shared__ __align__(16) unsigned short smem[16384];  // 32 KB
  int bid = ((blockIdx.x & 7) << 7) | (blockIdx.x >> 3);  // XCD swizzle
  size_t mbase = (size_t)(bid >> 2) * 128;
  int nbase = (bid & 3) * 128;
  int tid = threadIdx.x;
  int l = tid & 63, w = tid >> 6;
  int lr = l & 15, lg = l >> 4;
  int wr = (w >> 1) * 64, wc = (w & 1) * 64;

  const unsigned short* gA = A + (mbase + w * 32 + (l >> 2)) * 512 + (l & 3) * 8;
  const unsigned short* gB = BT + (size_t)(nbase + w * 32 + (l >> 2)) * 512 + (l & 3) * 8;

  // prologue: batch 0 -> buf0 (A@0, B@4096), batch 1 -> buf1 (A@8192, B@12288)
  GLDS16(gA, smem + w * 1024);
  GLDS16(gA + 16 * 512, smem + w * 1024 + 512);
  GLDS16(gB, smem + 4096 + w * 1024);
  GLDS16(gB + 16 * 512, smem + 4096 + w * 1024 + 512);
  GLDS16(gA + 32, smem + 8192 + w * 1024);
  GLDS16(gA + 32 + 16 * 512, smem + 8192 + w * 1024 + 512);
  GLDS16(gB + 32, smem + 12288 + w * 1024);
  GLDS16(gB + 32 + 16 * 512, smem + 12288 + w * 1024 + 512);

  f32x4 acc[4][4] = {};
#pragma unroll 1
  for (int t = 0; t < 16; t += 2) {
    KSTEP(t, 0);
    KSTEP(t + 1, 8192);
  }

#pragma unroll
  for (int m = 0; m < 4; ++m) {
#pragma unroll
    for (int n = 0; n < 4; ++n) {
#pragma unroll
      for (int reg = 0; reg < 4; ++reg) {
        size_t row = mbase + wr + m * 16 + lg * 4 + reg;
        int col = nbase + wc + n * 16 + lr;
        Out[row * 512 + col] = acc[m][n][reg] + bias[col];
      }
    }
  }
}

// ---------------------------------------------------------------------------
// Workspace layout (bytes)
// ---------------------------------------------------------------------------
static const size_t OFF_Q   = 0;                         // 8*4096*512*2 = 33554432
static const size_t OFF_KP  = 33554432;                  // 8*8*80*64*2  = 655360
static const size_t OFF_VT  = OFF_KP + 655360;           // 8*8*64*96*2  = 786432
static const size_t OFF_WQT = OFF_VT + 786432;           // 512*512*2
static const size_t OFF_WKT = OFF_WQT + 524288;          // 512*768*2
static const size_t OFF_WVT = OFF_WKT + 786432;          // 512*768*2
static const size_t OFF_WOT = OFF_WVT + 786432;          // 512*512*2
static const size_t WS_NEEDED = OFF_WOT + 524288;        // 37617664

extern "C" void kernel_launch(void* const* d_in, const int* in_sizes, int n_in,
                              void* d_out, int out_size, void* d_ws, size_t ws_size,
                              hipStream_t stream) {
  (void)in_sizes; (void)n_in; (void)out_size;
  if (ws_size < WS_NEEDED) return;

  const float* latent  = (const float*)d_in[0];
  const float* context = (const float*)d_in[1];
  const float* wq = (const float*)d_in[2];
  const float* bq = (const float*)d_in[3];
  const float* wk = (const float*)d_in[4];
  const float* bk = (const float*)d_in[5];
  const float* wv = (const float*)d_in[6];
  const float* bv = (const float*)d_in[7];
  const float* wo = (const float*)d_in[8];
  const float* bo = (const float*)d_in[9];
  float* out = (float*)d_out;

  char* ws = (char*)d_ws;
  unsigned short* wsQ = (unsigned short*)(ws + OFF_Q);   // attn output (bf16)
  unsigned short* Kp  = (unsigned short*)(ws + OFF_KP);
  unsigned short* Vt  = (unsigned short*)(ws + OFF_VT);
  unsigned short* wqT = (unsigned short*)(ws + OFF_WQT);
  unsigned short* wkT = (unsigned short*)(ws + OFF_WKT);
  unsigned short* wvT = (unsigned short*)(ws + OFF_WVT);
  unsigned short* woT = (unsigned short*)(ws + OFF_WOT);

  // latent bf16 parked in d_out (first 33.5MB); consumed by qproj, then
  // d_out fully rewritten by the final GEMM.
  unsigned short* latBF = (unsigned short*)d_out;

  prep_kernel<<<1280 + 8192, 256, 0, stream>>>(wq, wk, wv, wo, wqT, wkT, wvT,
                                               woT, latent,
                                               (unsigned int*)latBF);
  hipMemsetAsync(ws + OFF_KP, 0, 655360 + 786432, stream);
  kv_proj_kernel<<<160, 256, 0, stream>>>(context, wkT, wvT, bk, bv, Kp, Vt);
  qproj_attn_kernel<<<1024, 256, 0, stream>>>(latBF, wqT, bq, Kp, Vt, wsQ);
  gemm512_glds_kernel<<<1024, 256, 0, stream>>>(wsQ, woT, bo, out);
}

// Round 11
// 119.363 us; speedup vs baseline: 1.1498x; 1.0479x over previous
//
#include <hip/hip_runtime.h>

// CrossAttention on MI355X (gfx950), round 11.
// B=8 SQ=4096 SKV=77 DE=512 DC=768 H=8 DH=64.
// R11 (base = R10, 125us): eliminate the standalone latent fp32->bf16 pass.
// qproj stages A directly as fp32 via global_load_lds ([128][32] f32 tile,
// 16KB/buf) and converts to bf16 at fragment-read time with v_cvt_pk_bf16_f32
// (RNE, verified R6). LDS 48KB -> 3 blocks/CU. vmcnt(6) steady (12 in
// flight: 6 GLDS/wave/step x 2 buffers). O-GEMM and attn tail unchanged.

typedef __attribute__((ext_vector_type(8))) __bf16 bf16x8;
typedef __attribute__((ext_vector_type(4))) float f32x4;

#define DEVI static __device__ __forceinline__

typedef __attribute__((address_space(3))) void lds_void_t;
typedef const __attribute__((address_space(1))) void gbl_void_t;
#define GLDS16(gsrc, ldst) \
  __builtin_amdgcn_global_load_lds((gbl_void_t*)(gsrc), (lds_void_t*)(ldst), 16, 0, 0)

DEVI unsigned short f2bf(float f) {
  unsigned int u = __float_as_uint(f);
  u += 0x7FFFu + ((u >> 16) & 1u);   // round-to-nearest-even
  return (unsigned short)(u >> 16);
}

DEVI unsigned int cvt_pk_bf16(float lo, float hi) {
  unsigned int r;
  asm("v_cvt_pk_bf16_f32 %0, %1, %2" : "=v"(r) : "v"(lo), "v"(hi));
  return r;
}

DEVI bf16x8 cvt8(float4 a, float4 b) {
  uint4 u;
  u.x = cvt_pk_bf16(a.x, a.y);
  u.y = cvt_pk_bf16(a.z, a.w);
  u.z = cvt_pk_bf16(b.x, b.y);
  u.w = cvt_pk_bf16(b.z, b.w);
  return *(bf16x8*)&u;
}

// ---------------------------------------------------------------------------
// All 4 weight transposes in one launch. in [K][N=512] f32 -> out [N][K] bf16.
// ---------------------------------------------------------------------------
__global__ __launch_bounds__(256) void wtrans_all_kernel(
    const float* __restrict__ wq, const float* __restrict__ wk,
    const float* __restrict__ wv, const float* __restrict__ wo,
    unsigned short* __restrict__ wqT, unsigned short* __restrict__ wkT,
    unsigned short* __restrict__ wvT, unsigned short* __restrict__ woT) {
  __shared__ float tile[32][33];
  int bid = blockIdx.x;
  int tid = threadIdx.x;
  const float* in;
  unsigned short* out;
  int K, r;
  if (bid < 256)       { in = wq; out = wqT; K = 512; r = bid; }
  else if (bid < 640)  { in = wk; out = wkT; K = 768; r = bid - 256; }
  else if (bid < 1024) { in = wv; out = wvT; K = 768; r = bid - 640; }
  else                 { in = wo; out = woT; K = 512; r = bid - 1024; }
  int n0 = (r & 15) * 32, k0 = (r >> 4) * 32;
  int tx = tid & 31, ty = tid >> 5;
#pragma unroll
  for (int j = 0; j < 4; ++j)
    tile[ty * 4 + j][tx] = in[(size_t)(k0 + ty * 4 + j) * 512 + n0 + tx];
  __syncthreads();
#pragma unroll
  for (int j = 0; j < 4; ++j)
    out[(size_t)(n0 + ty * 4 + j) * K + k0 + tx] = f2bf(tile[tx][ty * 4 + j]);
}

// ---------------------------------------------------------------------------
// K/V projection (unchanged, proven)
// ---------------------------------------------------------------------------
__global__ __launch_bounds__(256) void kv_proj_kernel(const float* __restrict__ ctx,
                                                      const unsigned short* __restrict__ wkT,
                                                      const unsigned short* __restrict__ wvT,
                                                      const float* __restrict__ bk,
                                                      const float* __restrict__ bv,
                                                      unsigned short* __restrict__ Kp,
                                                      unsigned short* __restrict__ Vt) {
  __shared__ __align__(16) unsigned short As[64][40];
  __shared__ __align__(16) unsigned short Bs[64][40];
  int bid = blockIdx.x;
  int sel = bid / 80;
  int rem = bid % 80;
  int mt = rem / 8, nt = rem % 8;
  const unsigned short* wT = sel ? wvT : wkT;
  const float* bias = sel ? bv : bk;
  int tid = threadIdx.x;
  int l = tid & 63, w = tid >> 6;
  int lr = l & 15, lg = l >> 4;

  f32x4 acc[4] = {};
  for (int k0 = 0; k0 < 768; k0 += 32) {
#pragma unroll
    for (int it = 0; it < 2; ++it) {
      int idx4 = it * 256 + tid;
      int r = idx4 >> 3, q4 = idx4 & 7;
      int m = mt * 64 + r;
      float4 v = {0.f, 0.f, 0.f, 0.f};
      if (m < 616) v = *(const float4*)(ctx + (size_t)m * 768 + k0 + q4 * 4);
      ushort4 o;
      o.x = f2bf(v.x); o.y = f2bf(v.y); o.z = f2bf(v.z); o.w = f2bf(v.w);
      *(ushort4*)&As[r][q4 * 4] = o;
    }
    {
      int c = tid >> 2, q8 = tid & 3;
      *(uint4*)&Bs[c][q8 * 8] =
          *(const uint4*)(wT + (size_t)(nt * 64 + c) * 768 + k0 + q8 * 8);
    }
    __syncthreads();
    bf16x8 a = *(const bf16x8*)&As[w * 16 + lr][lg * 8];
#pragma unroll
    for (int n = 0; n < 4; ++n) {
      bf16x8 bb = *(const bf16x8*)&Bs[n * 16 + lr][lg * 8];
      acc[n] = __builtin_amdgcn_mfma_f32_16x16x32_bf16(a, bb, acc[n], 0, 0, 0);
    }
    __syncthreads();
  }
#pragma unroll
  for (int n = 0; n < 4; ++n) {
#pragma unroll
    for (int reg = 0; reg < 4; ++reg) {
      int m = mt * 64 + w * 16 + lg * 4 + reg;
      if (m < 616) {
        int bI = m / 77, s = m % 77;
        int col = nt * 64 + n * 16 + lr;
        int h = col >> 6, d = col & 63;
        float v = acc[n][reg] + bias[col];
        if (sel == 0)
          Kp[(((size_t)(bI * 8 + h)) * 80 + s) * 64 + d] = f2bf(v);
        else
          Vt[(((size_t)(bI * 8 + h)) * 64 + d) * 96 + s] = f2bf(v);
      }
    }
  }
}

// ---------------------------------------------------------------------------
// qproj K-step: A staged fp32 [128][32] (AO, 8192 u16), B bf16 [128][32]
// (BO, 4096 u16). Per wave per step: 4 A-GLDS + 2 B-GLDS. vmcnt(6) steady.
// ---------------------------------------------------------------------------
#define QSTEP(t, AO, BO)                                                      \
  {                                                                           \
    if ((t) < 15)                                                             \
      asm volatile("s_waitcnt vmcnt(6)" ::: "memory");                        \
    else                                                                      \
      asm volatile("s_waitcnt vmcnt(0)" ::: "memory");                        \
    __builtin_amdgcn_s_barrier();                                             \
    __builtin_amdgcn_sched_barrier(0);                                        \
    const float* Af = (const float*)(smem + (AO));                            \
    const unsigned short* Bf = smem + (BO);                                   \
    float4 ax[4], ay[4];                                                      \
    bf16x8 bv8[4];                                                            \
    _Pragma("unroll") for (int m = 0; m < 4; ++m) {                           \
      ax[m] = *(const float4*)&Af[(wr + m * 16 + lr) * 32 + lg * 8];          \
      ay[m] = *(const float4*)&Af[(wr + m * 16 + lr) * 32 + lg * 8 + 4];      \
    }                                                                         \
    _Pragma("unroll") for (int n = 0; n < 4; ++n)                             \
        bv8[n] = *(const bf16x8*)&Bf[(wc + n * 16 + lr) * 32 + lg * 8];       \
    asm volatile("s_waitcnt lgkmcnt(0)" ::: "memory");                        \
    __builtin_amdgcn_sched_barrier(0);                                        \
    __builtin_amdgcn_s_barrier();                                             \
    if ((t) <= 13) {                                                          \
      int nk = ((t) + 2) * 32;                                                \
      _Pragma("unroll") for (int i = 0; i < 4; ++i)                           \
          GLDS16(gA32 + nk + i * 4096, smem + (AO) + w * 2048 + i * 512);     \
      GLDS16(gB + nk, smem + (BO) + w * 1024);                                \
      GLDS16(gB + nk + 16 * 512, smem + (BO) + w * 1024 + 512);               \
    }                                                                         \
    bf16x8 af[4];                                                             \
    _Pragma("unroll") for (int m = 0; m < 4; ++m) af[m] = cvt8(ax[m], ay[m]); \
    _Pragma("unroll") for (int m = 0; m < 4; ++m)                             \
        _Pragma("unroll") for (int n = 0; n < 4; ++n)                         \
            acc[m][n] = __builtin_amdgcn_mfma_f32_16x16x32_bf16(              \
                af[m], bv8[n], acc[m][n], 0, 0, 0);                           \
  }

// ---------------------------------------------------------------------------
// FUSED Q-proj + attention: fp32-A staging + counted-vmcnt + attn tail.
// LDS layout (u16 elems): A0@0(8192) B0@8192(4096) A1@12288(8192)
// B1@20480(4096) = 24576 u16 = 49152 B -> 3 blocks/CU. Attn Qw overlay
// [4][64][72] = 18432 u16 fits at base.
// ---------------------------------------------------------------------------
__global__ __launch_bounds__(256, 3) void qproj_attn_kernel(
    const float* __restrict__ A32, const unsigned short* __restrict__ BT,
    const float* __restrict__ bias, const unsigned short* __restrict__ Kp,
    const unsigned short* __restrict__ Vt, unsigned short* __restrict__ Oq) {
  __shared__ __align__(16) unsigned short smem[24576];  // 49152 B

  int bid = ((blockIdx.x & 7) << 7) | (blockIdx.x >> 3);  // XCD swizzle
  size_t mbase = (size_t)(bid >> 2) * 128;
  int nbase = (bid & 3) * 128;
  int tid = threadIdx.x;
  int l = tid & 63, w = tid >> 6;
  int lr = l & 15, lg = l >> 4;
  int wr = (w >> 1) * 64, wc = (w & 1) * 64;

  // A (fp32): chunk idx = i*64+l covers row i*8+(l>>3), quarter (l&7)
  const float* gA32 = A32 + (mbase + w * 32 + (l >> 3)) * 512 + (l & 7) * 4;
  // B (bf16): chunk idx = i*64+l covers row i*16+(l>>2), quarter (l&3)
  const unsigned short* gB = BT + (size_t)(nbase + w * 32 + (l >> 2)) * 512 + (l & 3) * 8;

  // prologue: batch 0 -> A0/B0, batch 1 -> A1/B1
#pragma unroll
  for (int i = 0; i < 4; ++i) GLDS16(gA32 + i * 4096, smem + w * 2048 + i * 512);
  GLDS16(gB, smem + 8192 + w * 1024);
  GLDS16(gB + 16 * 512, smem + 8192 + w * 1024 + 512);
#pragma unroll
  for (int i = 0; i < 4; ++i)
    GLDS16(gA32 + 32 + i * 4096, smem + 12288 + w * 2048 + i * 512);
  GLDS16(gB + 32, smem + 20480 + w * 1024);
  GLDS16(gB + 32 + 16 * 512, smem + 20480 + w * 1024 + 512);

  f32x4 acc[4][4] = {};
#pragma unroll 1
  for (int t = 0; t < 16; t += 2) {
    QSTEP(t, 0, 8192);
    QSTEP(t + 1, 12288, 20480);
  }

  // ---- epilogue: Q quadrant -> wave-private LDS (transpose), +bias ----
  // Final step's second barrier guaranteed all waves' ds_reads complete.
  unsigned short* Qme = smem + w * (64 * 72);
  float bb[4];
#pragma unroll
  for (int n = 0; n < 4; ++n) bb[n] = bias[nbase + wc + n * 16 + lr];
#pragma unroll
  for (int m = 0; m < 4; ++m)
#pragma unroll
    for (int n = 0; n < 4; ++n)
#pragma unroll
      for (int reg = 0; reg < 4; ++reg)
        Qme[(m * 16 + lg * 4 + reg) * 72 + n * 16 + lr] = f2bf(acc[m][n][reg] + bb[n]);

  bf16x8 qf[4][2];
#pragma unroll
  for (int rg = 0; rg < 4; ++rg) {
    qf[rg][0] = *(const bf16x8*)&Qme[(rg * 16 + lr) * 72 + lg * 8];
    qf[rg][1] = *(const bf16x8*)&Qme[(rg * 16 + lr) * 72 + 32 + lg * 8];
  }

  // wave-private P inside this wave's dead Qw region (16 x 104 bf16)
  unsigned short* Pme = Qme;
  for (int z = l; z < 256; z += 64) Pme[(z >> 4) * 104 + 80 + (z & 15)] = 0;

  // ---- wave-local attention: 64 q-rows x head h ----
  int b = (int)(mbase >> 12);
  int h = (bid & 3) * 2 + (w & 1);
  const unsigned short* Kph = Kp + (size_t)(b * 8 + h) * (80 * 64);
  const unsigned short* Vth = Vt + (size_t)(b * 8 + h) * (64 * 96);

  const float C = 0.125f * 1.44269504088896f;  // 1/sqrt(64) * log2(e)

  auto QK = [&](int rg, f32x4* s) {
#pragma unroll
    for (int t = 0; t < 5; ++t) {
      const unsigned short* kr = Kph + (t * 16 + lr) * 64 + lg * 8;
      bf16x8 k0 = *(const bf16x8*)kr;
      bf16x8 k1 = *(const bf16x8*)(kr + 32);
      s[t] = __builtin_amdgcn_mfma_f32_16x16x32_bf16(qf[rg][0], k0, s[t], 0, 0, 0);
      s[t] = __builtin_amdgcn_mfma_f32_16x16x32_bf16(qf[rg][1], k1, s[t], 0, 0, 0);
    }
    if (lr >= 13) {  // cols 64+lr >= 77 are pad
      s[4][0] = -1e30f; s[4][1] = -1e30f; s[4][2] = -1e30f; s[4][3] = -1e30f;
    }
  };

  f32x4 sc[5] = {};
  QK(0, sc);
#pragma unroll
  for (int rg = 0; rg < 4; ++rg) {
    float mx[4];
#pragma unroll
    for (int r = 0; r < 4; ++r)
      mx[r] = fmaxf(fmaxf(fmaxf(sc[0][r], sc[1][r]), fmaxf(sc[2][r], sc[3][r])), sc[4][r]);
#pragma unroll
    for (int d = 1; d < 16; d <<= 1)
#pragma unroll
      for (int r = 0; r < 4; ++r) mx[r] = fmaxf(mx[r], __shfl_xor(mx[r], d, 64));
    float p[5][4];
#pragma unroll
    for (int t = 0; t < 5; ++t)
#pragma unroll
      for (int r = 0; r < 4; ++r) p[t][r] = exp2f((sc[t][r] - mx[r]) * C);
#pragma unroll
    for (int t = 0; t < 5; ++t)
#pragma unroll
      for (int r = 0; r < 4; ++r)
        Pme[(lg * 4 + r) * 104 + t * 16 + lr] = f2bf(p[t][r]);

    float sm[4];
#pragma unroll
    for (int r = 0; r < 4; ++r)
      sm[r] = p[0][r] + p[1][r] + p[2][r] + p[3][r] + p[4][r];
#pragma unroll
    for (int d = 1; d < 16; d <<= 1)
#pragma unroll
      for (int r = 0; r < 4; ++r) sm[r] += __shfl_xor(sm[r], d, 64);
    float rs[4];
#pragma unroll
    for (int r = 0; r < 4; ++r) rs[r] = 1.0f / sm[r];

    f32x4 sn[5] = {};
    if (rg < 3) QK(rg + 1, sn);

    bf16x8 ap[3];
#pragma unroll
    for (int c = 0; c < 3; ++c) ap[c] = *(const bf16x8*)&Pme[lr * 104 + c * 32 + lg * 8];
#pragma unroll
    for (int ct = 0; ct < 4; ++ct) {
      f32x4 o = {};
#pragma unroll
      for (int c = 0; c < 3; ++c) {
        bf16x8 vv = *(const bf16x8*)(Vth + (size_t)(ct * 16 + lr) * 96 + c * 32 + lg * 8);
        o = __builtin_amdgcn_mfma_f32_16x16x32_bf16(ap[c], vv, o, 0, 0, 0);
      }
#pragma unroll
      for (int reg = 0; reg < 4; ++reg)
        Oq[(mbase + wr + rg * 16 + lg * 4 + reg) * 512 + nbase + wc + ct * 16 + lr] =
            f2bf(o[reg] * rs[reg]);
    }
#pragma unroll
    for (int t = 0; t < 5; ++t) sc[t] = sn[t];
  }
}

// ---------------------------------------------------------------------------
// O-proj K-step (bf16 A, unchanged R10 geometry): buffer b at b*8192,
// A at +0, B at +4096. 4 GLDS/wave/step; vmcnt(4) steady.
// ---------------------------------------------------------------------------
#define KSTEP(t, boff)                                                        \
  {                                                                           \
    if ((t) < 15)                                                             \
      asm volatile("s_waitcnt vmcnt(4)" ::: "memory");                        \
    else                                                                      \
      asm volatile("s_waitcnt vmcnt(0)" ::: "memory");                        \
    __builtin_amdgcn_s_barrier();                                             \
    __builtin_amdgcn_sched_barrier(0);                                        \
    const unsigned short* bufA = smem + (boff);                               \
    const unsigned short* bufB = bufA + 4096;                                 \
    bf16x8 af[4], bv8[4];                                                     \
    _Pragma("unroll") for (int m = 0; m < 4; ++m)                             \
        af[m] = *(const bf16x8*)&bufA[(wr + m * 16 + lr) * 32 + lg * 8];      \
    _Pragma("unroll") for (int n = 0; n < 4; ++n)                             \
        bv8[n] = *(const bf16x8*)&bufB[(wc + n * 16 + lr) * 32 + lg * 8];     \
    asm volatile("s_waitcnt lgkmcnt(0)" ::: "memory");                        \
    __builtin_amdgcn_sched_barrier(0);                                        \
    __builtin_amdgcn_s_barrier();                                             \
    if ((t) <= 13) {                                                          \
      int nk = ((t) + 2) * 32;                                                \
      GLDS16(gA + nk, smem + (boff) + w * 1024);                              \
      GLDS16(gA + nk + 16 * 512, smem + (boff) + w * 1024 + 512);             \
      GLDS16(gB + nk, smem + (boff) + 4096 + w * 1024);                       \
      GLDS16(gB + nk + 16 * 512, smem + (boff) + 4096 + w * 1024 + 512);      \
    }                                                                         \
    _Pragma("unroll") for (int m = 0; m < 4; ++m)                             \
        _Pragma("unroll") for (int n = 0; n < 4; ++n)                         \
            acc[m][n] = __builtin_amdgcn_mfma_f32_16x16x32_bf16(              \
                af[m], bv8[n], acc[m][n], 0, 0, 0);                           \
  }

__global__ __launch_bounds__(256) void gemm512_glds_kernel(
    const unsigned short* __restrict__ A, const unsigned short* __restrict__ BT,
    const float* __restrict__ bias, float* __restrict__ Out) {
  __shared__ __align__(16) unsigned short smem[16384];  // 32 KB
  int bid = ((blockIdx.x & 7) << 7) | (blockIdx.x >> 3);  // XCD swizzle
  size_t mbase = (size_t)(bid >> 2) * 128;
  int nbase = (bid & 3) * 128;
  int tid = threadIdx.x;
  int l = tid & 63, w = tid >> 6;
  int lr = l & 15, lg = l >> 4;
  int wr = (w >> 1) * 64, wc = (w & 1) * 64;

  const unsigned short* gA = A + (mbase + w * 32 + (l >> 2)) * 512 + (l & 3) * 8;
  const unsigned short* gB = BT + (size_t)(nbase + w * 32 + (l >> 2)) * 512 + (l & 3) * 8;

  GLDS16(gA, smem + w * 1024);
  GLDS16(gA + 16 * 512, smem + w * 1024 + 512);
  GLDS16(gB, smem + 4096 + w * 1024);
  GLDS16(gB + 16 * 512, smem + 4096 + w * 1024 + 512);
  GLDS16(gA + 32, smem + 8192 + w * 1024);
  GLDS16(gA + 32 + 16 * 512, smem + 8192 + w * 1024 + 512);
  GLDS16(gB + 32, smem + 12288 + w * 1024);
  GLDS16(gB + 32 + 16 * 512, smem + 12288 + w * 1024 + 512);

  f32x4 acc[4][4] = {};
#pragma unroll 1
  for (int t = 0; t < 16; t += 2) {
    KSTEP(t, 0);
    KSTEP(t + 1, 8192);
  }

#pragma unroll
  for (int m = 0; m < 4; ++m) {
#pragma unroll
    for (int n = 0; n < 4; ++n) {
#pragma unroll
      for (int reg = 0; reg < 4; ++reg) {
        size_t row = mbase + wr + m * 16 + lg * 4 + reg;
        int col = nbase + wc + n * 16 + lr;
        Out[row * 512 + col] = acc[m][n][reg] + bias[col];
      }
    }
  }
}

// ---------------------------------------------------------------------------
// Workspace layout (bytes)
// ---------------------------------------------------------------------------
static const size_t OFF_Q   = 0;                         // 8*4096*512*2 = 33554432
static const size_t OFF_KP  = 33554432;                  // 8*8*80*64*2  = 655360
static const size_t OFF_VT  = OFF_KP + 655360;           // 8*8*64*96*2  = 786432
static const size_t OFF_WQT = OFF_VT + 786432;           // 512*512*2
static const size_t OFF_WKT = OFF_WQT + 524288;          // 512*768*2
static const size_t OFF_WVT = OFF_WKT + 786432;          // 512*768*2
static const size_t OFF_WOT = OFF_WVT + 786432;          // 512*512*2
static const size_t WS_NEEDED = OFF_WOT + 524288;        // 37617664

extern "C" void kernel_launch(void* const* d_in, const int* in_sizes, int n_in,
                              void* d_out, int out_size, void* d_ws, size_t ws_size,
                              hipStream_t stream) {
  (void)in_sizes; (void)n_in; (void)out_size;
  if (ws_size < WS_NEEDED) return;

  const float* latent  = (const float*)d_in[0];
  const float* context = (const float*)d_in[1];
  const float* wq = (const float*)d_in[2];
  const float* bq = (const float*)d_in[3];
  const float* wk = (const float*)d_in[4];
  const float* bk = (const float*)d_in[5];
  const float* wv = (const float*)d_in[6];
  const float* bv = (const float*)d_in[7];
  const float* wo = (const float*)d_in[8];
  const float* bo = (const float*)d_in[9];
  float* out = (float*)d_out;

  char* ws = (char*)d_ws;
  unsigned short* wsQ = (unsigned short*)(ws + OFF_Q);   // attn output (bf16)
  unsigned short* Kp  = (unsigned short*)(ws + OFF_KP);
  unsigned short* Vt  = (unsigned short*)(ws + OFF_VT);
  unsigned short* wqT = (unsigned short*)(ws + OFF_WQT);
  unsigned short* wkT = (unsigned short*)(ws + OFF_WKT);
  unsigned short* wvT = (unsigned short*)(ws + OFF_WVT);
  unsigned short* woT = (unsigned short*)(ws + OFF_WOT);

  wtrans_all_kernel<<<1280, 256, 0, stream>>>(wq, wk, wv, wo,
                                              wqT, wkT, wvT, woT);
  hipMemsetAsync(ws + OFF_KP, 0, 655360 + 786432, stream);
  kv_proj_kernel<<<160, 256, 0, stream>>>(context, wkT, wvT, bk, bv, Kp, Vt);
  qproj_attn_kernel<<<1024, 256, 0, stream>>>(latent, wqT, bq, Kp, Vt, wsQ);
  gemm512_glds_kernel<<<1024, 256, 0, stream>>>(wsQ, woT, bo, out);
}

// Round 12
// 114.604 us; speedup vs baseline: 1.1975x; 1.0415x over previous
//
#include <hip/hip_runtime.h>

// CrossAttention on MI355X (gfx950), round 12.
// B=8 SQ=4096 SKV=77 DE=512 DC=768 H=8 DH=64.
// R12 (base = R11, 119.4us): XOR bank-conflict swizzles on all GEMM LDS
// tiles (rule 21: linear GLDS dest + inverse-swizzled SOURCE + swizzled
// READ; XOR is an involution).
//   A-fp32 [128r x 128B]: slot' = slot ^ (row&7)      (was ~16-way)
//   bf16   [128r x  64B]: slot' = slot ^ ((row>>1)&3) (was ~8-way)
// Everything else identical to R11.

typedef __attribute__((ext_vector_type(8))) __bf16 bf16x8;
typedef __attribute__((ext_vector_type(4))) float f32x4;

#define DEVI static __device__ __forceinline__

typedef __attribute__((address_space(3))) void lds_void_t;
typedef const __attribute__((address_space(1))) void gbl_void_t;
#define GLDS16(gsrc, ldst) \
  __builtin_amdgcn_global_load_lds((gbl_void_t*)(gsrc), (lds_void_t*)(ldst), 16, 0, 0)

DEVI unsigned short f2bf(float f) {
  unsigned int u = __float_as_uint(f);
  u += 0x7FFFu + ((u >> 16) & 1u);   // round-to-nearest-even
  return (unsigned short)(u >> 16);
}

DEVI unsigned int cvt_pk_bf16(float lo, float hi) {
  unsigned int r;
  asm("v_cvt_pk_bf16_f32 %0, %1, %2" : "=v"(r) : "v"(lo), "v"(hi));
  return r;
}

DEVI bf16x8 cvt8(float4 a, float4 b) {
  uint4 u;
  u.x = cvt_pk_bf16(a.x, a.y);
  u.y = cvt_pk_bf16(a.z, a.w);
  u.z = cvt_pk_bf16(b.x, b.y);
  u.w = cvt_pk_bf16(b.z, b.w);
  return *(bf16x8*)&u;
}

// ---------------------------------------------------------------------------
// All 4 weight transposes in one launch. in [K][N=512] f32 -> out [N][K] bf16.
// ---------------------------------------------------------------------------
__global__ __launch_bounds__(256) void wtrans_all_kernel(
    const float* __restrict__ wq, const float* __restrict__ wk,
    const float* __restrict__ wv, const float* __restrict__ wo,
    unsigned short* __restrict__ wqT, unsigned short* __restrict__ wkT,
    unsigned short* __restrict__ wvT, unsigned short* __restrict__ woT) {
  __shared__ float tile[32][33];
  int bid = blockIdx.x;
  int tid = threadIdx.x;
  const float* in;
  unsigned short* out;
  int K, r;
  if (bid < 256)       { in = wq; out = wqT; K = 512; r = bid; }
  else if (bid < 640)  { in = wk; out = wkT; K = 768; r = bid - 256; }
  else if (bid < 1024) { in = wv; out = wvT; K = 768; r = bid - 640; }
  else                 { in = wo; out = woT; K = 512; r = bid - 1024; }
  int n0 = (r & 15) * 32, k0 = (r >> 4) * 32;
  int tx = tid & 31, ty = tid >> 5;
#pragma unroll
  for (int j = 0; j < 4; ++j)
    tile[ty * 4 + j][tx] = in[(size_t)(k0 + ty * 4 + j) * 512 + n0 + tx];
  __syncthreads();
#pragma unroll
  for (int j = 0; j < 4; ++j)
    out[(size_t)(n0 + ty * 4 + j) * K + k0 + tx] = f2bf(tile[tx][ty * 4 + j]);
}

// ---------------------------------------------------------------------------
// K/V projection (unchanged, proven)
// ---------------------------------------------------------------------------
__global__ __launch_bounds__(256) void kv_proj_kernel(const float* __restrict__ ctx,
                                                      const unsigned short* __restrict__ wkT,
                                                      const unsigned short* __restrict__ wvT,
                                                      const float* __restrict__ bk,
                                                      const float* __restrict__ bv,
                                                      unsigned short* __restrict__ Kp,
                                                      unsigned short* __restrict__ Vt) {
  __shared__ __align__(16) unsigned short As[64][40];
  __shared__ __align__(16) unsigned short Bs[64][40];
  int bid = blockIdx.x;
  int sel = bid / 80;
  int rem = bid % 80;
  int mt = rem / 8, nt = rem % 8;
  const unsigned short* wT = sel ? wvT : wkT;
  const float* bias = sel ? bv : bk;
  int tid = threadIdx.x;
  int l = tid & 63, w = tid >> 6;
  int lr = l & 15, lg = l >> 4;

  f32x4 acc[4] = {};
  for (int k0 = 0; k0 < 768; k0 += 32) {
#pragma unroll
    for (int it = 0; it < 2; ++it) {
      int idx4 = it * 256 + tid;
      int r = idx4 >> 3, q4 = idx4 & 7;
      int m = mt * 64 + r;
      float4 v = {0.f, 0.f, 0.f, 0.f};
      if (m < 616) v = *(const float4*)(ctx + (size_t)m * 768 + k0 + q4 * 4);
      ushort4 o;
      o.x = f2bf(v.x); o.y = f2bf(v.y); o.z = f2bf(v.z); o.w = f2bf(v.w);
      *(ushort4*)&As[r][q4 * 4] = o;
    }
    {
      int c = tid >> 2, q8 = tid & 3;
      *(uint4*)&Bs[c][q8 * 8] =
          *(const uint4*)(wT + (size_t)(nt * 64 + c) * 768 + k0 + q8 * 8);
    }
    __syncthreads();
    bf16x8 a = *(const bf16x8*)&As[w * 16 + lr][lg * 8];
#pragma unroll
    for (int n = 0; n < 4; ++n) {
      bf16x8 bb = *(const bf16x8*)&Bs[n * 16 + lr][lg * 8];
      acc[n] = __builtin_amdgcn_mfma_f32_16x16x32_bf16(a, bb, acc[n], 0, 0, 0);
    }
    __syncthreads();
  }
#pragma unroll
  for (int n = 0; n < 4; ++n) {
#pragma unroll
    for (int reg = 0; reg < 4; ++reg) {
      int m = mt * 64 + w * 16 + lg * 4 + reg;
      if (m < 616) {
        int bI = m / 77, s = m % 77;
        int col = nt * 64 + n * 16 + lr;
        int h = col >> 6, d = col & 63;
        float v = acc[n][reg] + bias[col];
        if (sel == 0)
          Kp[(((size_t)(bI * 8 + h)) * 80 + s) * 64 + d] = f2bf(v);
        else
          Vt[(((size_t)(bI * 8 + h)) * 64 + d) * 96 + s] = f2bf(v);
      }
    }
  }
}

// ---------------------------------------------------------------------------
// qproj K-step: A fp32 [128][32]f (slot^=(row&7)), B bf16 [128][32]
// (slot^=((row>>1)&3)). 6 GLDS/wave/step; vmcnt(6) steady.
// ---------------------------------------------------------------------------
#define QSTEP(t, AO, BO)                                                      \
  {                                                                           \
    if ((t) < 15)                                                             \
      asm volatile("s_waitcnt vmcnt(6)" ::: "memory");                        \
    else                                                                      \
      asm volatile("s_waitcnt vmcnt(0)" ::: "memory");                        \
    __builtin_amdgcn_s_barrier();                                             \
    __builtin_amdgcn_sched_barrier(0);                                        \
    const float* Af = (const float*)(smem + (AO));                            \
    const unsigned short* Bf = smem + (BO);                                   \
    const int swA = lr & 7;                                                   \
    const int swB = (lr >> 1) & 3;                                            \
    float4 ax[4], ay[4];                                                      \
    bf16x8 bv8[4];                                                            \
    _Pragma("unroll") for (int m = 0; m < 4; ++m) {                           \
      ax[m] = *(const float4*)&Af[(wr + m * 16 + lr) * 32 +                   \
                                  ((2 * lg) ^ swA) * 4];                      \
      ay[m] = *(const float4*)&Af[(wr + m * 16 + lr) * 32 +                   \
                                  ((2 * lg + 1) ^ swA) * 4];                  \
    }                                                                         \
    _Pragma("unroll") for (int n = 0; n < 4; ++n)                             \
        bv8[n] = *(const bf16x8*)&Bf[(wc + n * 16 + lr) * 32 +                \
                                     (lg ^ swB) * 8];                         \
    asm volatile("s_waitcnt lgkmcnt(0)" ::: "memory");                        \
    __builtin_amdgcn_sched_barrier(0);                                        \
    __builtin_amdgcn_s_barrier();                                             \
    if ((t) <= 13) {                                                          \
      int nk = ((t) + 2) * 32;                                                \
      _Pragma("unroll") for (int i = 0; i < 4; ++i)                           \
          GLDS16(gA32 + nk + i * 4096, smem + (AO) + w * 2048 + i * 512);     \
      GLDS16(gB + nk, smem + (BO) + w * 1024);                                \
      GLDS16(gB + nk + 16 * 512, smem + (BO) + w * 1024 + 512);               \
    }                                                                         \
    bf16x8 af[4];                                                             \
    _Pragma("unroll") for (int m = 0; m < 4; ++m) af[m] = cvt8(ax[m], ay[m]); \
    _Pragma("unroll") for (int m = 0; m < 4; ++m)                             \
        _Pragma("unroll") for (int n = 0; n < 4; ++n)                         \
            acc[m][n] = __builtin_amdgcn_mfma_f32_16x16x32_bf16(              \
                af[m], bv8[n], acc[m][n], 0, 0, 0);                           \
  }

// ---------------------------------------------------------------------------
// FUSED Q-proj + attention: fp32-A staging (swizzled) + counted-vmcnt +
// wave-private attn tail. LDS 49152 B -> 3 blocks/CU.
// ---------------------------------------------------------------------------
__global__ __launch_bounds__(256, 3) void qproj_attn_kernel(
    const float* __restrict__ A32, const unsigned short* __restrict__ BT,
    const float* __restrict__ bias, const unsigned short* __restrict__ Kp,
    const unsigned short* __restrict__ Vt, unsigned short* __restrict__ Oq) {
  __shared__ __align__(16) unsigned short smem[24576];  // 49152 B

  int bid = ((blockIdx.x & 7) << 7) | (blockIdx.x >> 3);  // XCD swizzle
  size_t mbase = (size_t)(bid >> 2) * 128;
  int nbase = (bid & 3) * 128;
  int tid = threadIdx.x;
  int l = tid & 63, w = tid >> 6;
  int lr = l & 15, lg = l >> 4;
  int wr = (w >> 1) * 64, wc = (w & 1) * 64;

  // A (fp32): dest (row = w*32+i*8+(l>>3), slot l&7); source slot pre-swizzled
  // by row&7 = l>>3 so that LDS holds slot' = slot ^ (row&7).
  const float* gA32 =
      A32 + (mbase + w * 32 + (l >> 3)) * 512 + (((l & 7) ^ (l >> 3))) * 4;
  // B (bf16): dest (row = i*16+(l>>2), slot l&3); source slot pre-swizzled by
  // (row>>1)&3 = (l>>3)&3.
  const unsigned short* gB = BT + (size_t)(nbase + w * 32 + (l >> 2)) * 512 +
                             (((l & 3) ^ ((l >> 3) & 3))) * 8;

  // prologue: batch 0 -> A0/B0, batch 1 -> A1/B1
#pragma unroll
  for (int i = 0; i < 4; ++i) GLDS16(gA32 + i * 4096, smem + w * 2048 + i * 512);
  GLDS16(gB, smem + 8192 + w * 1024);
  GLDS16(gB + 16 * 512, smem + 8192 + w * 1024 + 512);
#pragma unroll
  for (int i = 0; i < 4; ++i)
    GLDS16(gA32 + 32 + i * 4096, smem + 12288 + w * 2048 + i * 512);
  GLDS16(gB + 32, smem + 20480 + w * 1024);
  GLDS16(gB + 32 + 16 * 512, smem + 20480 + w * 1024 + 512);

  f32x4 acc[4][4] = {};
#pragma unroll 1
  for (int t = 0; t < 16; t += 2) {
    QSTEP(t, 0, 8192);
    QSTEP(t + 1, 12288, 20480);
  }

  // ---- epilogue: Q quadrant -> wave-private LDS (transpose), +bias ----
  unsigned short* Qme = smem + w * (64 * 72);
  float bb[4];
#pragma unroll
  for (int n = 0; n < 4; ++n) bb[n] = bias[nbase + wc + n * 16 + lr];
#pragma unroll
  for (int m = 0; m < 4; ++m)
#pragma unroll
    for (int n = 0; n < 4; ++n)
#pragma unroll
      for (int reg = 0; reg < 4; ++reg)
        Qme[(m * 16 + lg * 4 + reg) * 72 + n * 16 + lr] = f2bf(acc[m][n][reg] + bb[n]);

  bf16x8 qf[4][2];
#pragma unroll
  for (int rg = 0; rg < 4; ++rg) {
    qf[rg][0] = *(const bf16x8*)&Qme[(rg * 16 + lr) * 72 + lg * 8];
    qf[rg][1] = *(const bf16x8*)&Qme[(rg * 16 + lr) * 72 + 32 + lg * 8];
  }

  // wave-private P inside this wave's dead Qw region (16 x 104 bf16)
  unsigned short* Pme = Qme;
  for (int z = l; z < 256; z += 64) Pme[(z >> 4) * 104 + 80 + (z & 15)] = 0;

  // ---- wave-local attention: 64 q-rows x head h ----
  int b = (int)(mbase >> 12);
  int h = (bid & 3) * 2 + (w & 1);
  const unsigned short* Kph = Kp + (size_t)(b * 8 + h) * (80 * 64);
  const unsigned short* Vth = Vt + (size_t)(b * 8 + h) * (64 * 96);

  const float C = 0.125f * 1.44269504088896f;  // 1/sqrt(64) * log2(e)

  auto QK = [&](int rg, f32x4* s) {
#pragma unroll
    for (int t = 0; t < 5; ++t) {
      const unsigned short* kr = Kph + (t * 16 + lr) * 64 + lg * 8;
      bf16x8 k0 = *(const bf16x8*)kr;
      bf16x8 k1 = *(const bf16x8*)(kr + 32);
      s[t] = __builtin_amdgcn_mfma_f32_16x16x32_bf16(qf[rg][0], k0, s[t], 0, 0, 0);
      s[t] = __builtin_amdgcn_mfma_f32_16x16x32_bf16(qf[rg][1], k1, s[t], 0, 0, 0);
    }
    if (lr >= 13) {  // cols 64+lr >= 77 are pad
      s[4][0] = -1e30f; s[4][1] = -1e30f; s[4][2] = -1e30f; s[4][3] = -1e30f;
    }
  };

  f32x4 sc[5] = {};
  QK(0, sc);
#pragma unroll
  for (int rg = 0; rg < 4; ++rg) {
    float mx[4];
#pragma unroll
    for (int r = 0; r < 4; ++r)
      mx[r] = fmaxf(fmaxf(fmaxf(sc[0][r], sc[1][r]), fmaxf(sc[2][r], sc[3][r])), sc[4][r]);
#pragma unroll
    for (int d = 1; d < 16; d <<= 1)
#pragma unroll
      for (int r = 0; r < 4; ++r) mx[r] = fmaxf(mx[r], __shfl_xor(mx[r], d, 64));
    float p[5][4];
#pragma unroll
    for (int t = 0; t < 5; ++t)
#pragma unroll
      for (int r = 0; r < 4; ++r) p[t][r] = exp2f((sc[t][r] - mx[r]) * C);
#pragma unroll
    for (int t = 0; t < 5; ++t)
#pragma unroll
      for (int r = 0; r < 4; ++r)
        Pme[(lg * 4 + r) * 104 + t * 16 + lr] = f2bf(p[t][r]);

    float sm[4];
#pragma unroll
    for (int r = 0; r < 4; ++r)
      sm[r] = p[0][r] + p[1][r] + p[2][r] + p[3][r] + p[4][r];
#pragma unroll
    for (int d = 1; d < 16; d <<= 1)
#pragma unroll
      for (int r = 0; r < 4; ++r) sm[r] += __shfl_xor(sm[r], d, 64);
    float rs[4];
#pragma unroll
    for (int r = 0; r < 4; ++r) rs[r] = 1.0f / sm[r];

    f32x4 sn[5] = {};
    if (rg < 3) QK(rg + 1, sn);

    bf16x8 ap[3];
#pragma unroll
    for (int c = 0; c < 3; ++c) ap[c] = *(const bf16x8*)&Pme[lr * 104 + c * 32 + lg * 8];
#pragma unroll
    for (int ct = 0; ct < 4; ++ct) {
      f32x4 o = {};
#pragma unroll
      for (int c = 0; c < 3; ++c) {
        bf16x8 vv = *(const bf16x8*)(Vth + (size_t)(ct * 16 + lr) * 96 + c * 32 + lg * 8);
        o = __builtin_amdgcn_mfma_f32_16x16x32_bf16(ap[c], vv, o, 0, 0, 0);
      }
#pragma unroll
      for (int reg = 0; reg < 4; ++reg)
        Oq[(mbase + wr + rg * 16 + lg * 4 + reg) * 512 + nbase + wc + ct * 16 + lr] =
            f2bf(o[reg] * rs[reg]);
    }
#pragma unroll
    for (int t = 0; t < 5; ++t) sc[t] = sn[t];
  }
}

// ---------------------------------------------------------------------------
// O-proj K-step (bf16 A+B, both slot^=((row>>1)&3)). 4 GLDS/wave/step;
// vmcnt(4) steady. Buffer b at b*8192: A@+0, B@+4096.
// ---------------------------------------------------------------------------
#define KSTEP(t, boff)                                                        \
  {                                                                           \
    if ((t) < 15)                                                             \
      asm volatile("s_waitcnt vmcnt(4)" ::: "memory");                        \
    else                                                                      \
      asm volatile("s_waitcnt vmcnt(0)" ::: "memory");                        \
    __builtin_amdgcn_s_barrier();                                             \
    __builtin_amdgcn_sched_barrier(0);                                        \
    const unsigned short* bufA = smem + (boff);                               \
    const unsigned short* bufB = bufA + 4096;                                 \
    const int swB = (lr >> 1) & 3;                                            \
    bf16x8 af[4], bv8[4];                                                     \
    _Pragma("unroll") for (int m = 0; m < 4; ++m)                             \
        af[m] = *(const bf16x8*)&bufA[(wr + m * 16 + lr) * 32 +               \
                                      (lg ^ swB) * 8];                        \
    _Pragma("unroll") for (int n = 0; n < 4; ++n)                             \
        bv8[n] = *(const bf16x8*)&bufB[(wc + n * 16 + lr) * 32 +              \
                                       (lg ^ swB) * 8];                       \
    asm volatile("s_waitcnt lgkmcnt(0)" ::: "memory");                        \
    __builtin_amdgcn_sched_barrier(0);                                        \
    __builtin_amdgcn_s_barrier();                                             \
    if ((t) <= 13) {                                                          \
      int nk = ((t) + 2) * 32;                                                \
      GLDS16(gA + nk, smem + (boff) + w * 1024);                              \
      GLDS16(gA + nk + 16 * 512, smem + (boff) + w * 1024 + 512);             \
      GLDS16(gB + nk, smem + (boff) + 4096 + w * 1024);                       \
      GLDS16(gB + nk + 16 * 512, smem + (boff) + 4096 + w * 1024 + 512);      \
    }                                                                         \
    _Pragma("unroll") for (int m = 0; m < 4; ++m)                             \
        _Pragma("unroll") for (int n = 0; n < 4; ++n)                         \
            acc[m][n] = __builtin_amdgcn_mfma_f32_16x16x32_bf16(              \
                af[m], bv8[n], acc[m][n], 0, 0, 0);                           \
  }

__global__ __launch_bounds__(256) void gemm512_glds_kernel(
    const unsigned short* __restrict__ A, const unsigned short* __restrict__ BT,
    const float* __restrict__ bias, float* __restrict__ Out) {
  __shared__ __align__(16) unsigned short smem[16384];  // 32 KB
  int bid = ((blockIdx.x & 7) << 7) | (blockIdx.x >> 3);  // XCD swizzle
  size_t mbase = (size_t)(bid >> 2) * 128;
  int nbase = (bid & 3) * 128;
  int tid = threadIdx.x;
  int l = tid & 63, w = tid >> 6;
  int lr = l & 15, lg = l >> 4;
  int wr = (w >> 1) * 64, wc = (w & 1) * 64;

  // pre-swizzled sources: slot = (l&3) ^ ((row>>1)&3), row = w*32+i*16+(l>>2)
  // -> (row>>1)&3 = (l>>3)&3.
  const unsigned short* gA = A + (mbase + w * 32 + (l >> 2)) * 512 +
                             (((l & 3) ^ ((l >> 3) & 3))) * 8;
  const unsigned short* gB = BT + (size_t)(nbase + w * 32 + (l >> 2)) * 512 +
                             (((l & 3) ^ ((l >> 3) & 3))) * 8;

  GLDS16(gA, smem + w * 1024);
  GLDS16(gA + 16 * 512, smem + w * 1024 + 512);
  GLDS16(gB, smem + 4096 + w * 1024);
  GLDS16(gB + 16 * 512, smem + 4096 + w * 1024 + 512);
  GLDS16(gA + 32, smem + 8192 + w * 1024);
  GLDS16(gA + 32 + 16 * 512, smem + 8192 + w * 1024 + 512);
  GLDS16(gB + 32, smem + 12288 + w * 1024);
  GLDS16(gB + 32 + 16 * 512, smem + 12288 + w * 1024 + 512);

  f32x4 acc[4][4] = {};
#pragma unroll 1
  for (int t = 0; t < 16; t += 2) {
    KSTEP(t, 0);
    KSTEP(t + 1, 8192);
  }

#pragma unroll
  for (int m = 0; m < 4; ++m) {
#pragma unroll
    for (int n = 0; n < 4; ++n) {
#pragma unroll
      for (int reg = 0; reg < 4; ++reg) {
        size_t row = mbase + wr + m * 16 + lg * 4 + reg;
        int col = nbase + wc + n * 16 + lr;
        Out[row * 512 + col] = acc[m][n][reg] + bias[col];
      }
    }
  }
}

// ---------------------------------------------------------------------------
// Workspace layout (bytes)
// ---------------------------------------------------------------------------
static const size_t OFF_Q   = 0;                         // 8*4096*512*2 = 33554432
static const size_t OFF_KP  = 33554432;                  // 8*8*80*64*2  = 655360
static const size_t OFF_VT  = OFF_KP + 655360;           // 8*8*64*96*2  = 786432
static const size_t OFF_WQT = OFF_VT + 786432;           // 512*512*2
static const size_t OFF_WKT = OFF_WQT + 524288;          // 512*768*2
static const size_t OFF_WVT = OFF_WKT + 786432;          // 512*768*2
static const size_t OFF_WOT = OFF_WVT + 786432;          // 512*512*2
static const size_t WS_NEEDED = OFF_WOT + 524288;        // 37617664

extern "C" void kernel_launch(void* const* d_in, const int* in_sizes, int n_in,
                              void* d_out, int out_size, void* d_ws, size_t ws_size,
                              hipStream_t stream) {
  (void)in_sizes; (void)n_in; (void)out_size;
  if (ws_size < WS_NEEDED) return;

  const float* latent  = (const float*)d_in[0];
  const float* context = (const float*)d_in[1];
  const float* wq = (const float*)d_in[2];
  const float* bq = (const float*)d_in[3];
  const float* wk = (const float*)d_in[4];
  const float* bk = (const float*)d_in[5];
  const float* wv = (const float*)d_in[6];
  const float* bv = (const float*)d_in[7];
  const float* wo = (const float*)d_in[8];
  const float* bo = (const float*)d_in[9];
  float* out = (float*)d_out;

  char* ws = (char*)d_ws;
  unsigned short* wsQ = (unsigned short*)(ws + OFF_Q);   // attn output (bf16)
  unsigned short* Kp  = (unsigned short*)(ws + OFF_KP);
  unsigned short* Vt  = (unsigned short*)(ws + OFF_VT);
  unsigned short* wqT = (unsigned short*)(ws + OFF_WQT);
  unsigned short* wkT = (unsigned short*)(ws + OFF_WKT);
  unsigned short* wvT = (unsigned short*)(ws + OFF_WVT);
  unsigned short* woT = (unsigned short*)(ws + OFF_WOT);

  wtrans_all_kernel<<<1280, 256, 0, stream>>>(wq, wk, wv, wo,
                                              wqT, wkT, wvT, woT);
  hipMemsetAsync(ws + OFF_KP, 0, 655360 + 786432, stream);
  kv_proj_kernel<<<160, 256, 0, stream>>>(context, wkT, wvT, bk, bv, Kp, Vt);
  qproj_attn_kernel<<<1024, 256, 0, stream>>>(latent, wqT, bq, Kp, Vt, wsQ);
  gemm512_glds_kernel<<<1024, 256, 0, stream>>>(wsQ, woT, bo, out);
}